// Round 7
// baseline (153.434 us; speedup 1.0000x reference)
//
#include <hip/hip_runtime.h>
#include <hip/hip_fp16.h>
#include <math.h>

#define KSIZE 31
#define HRAD 15
#define NBUCK 48

union H4U { float2 f2; __half h[4]; };
union H8U { float4 f4; __half h[8]; };

// ---------------------------------------------------------------------------
// Cube-map coordinate math (mirrors reference cube_sample exactly, f32)
// ---------------------------------------------------------------------------
__device__ inline void cube_coords(float x, float y, float z,
                                   int& face, float& u, float& v) {
    float ax = fabsf(x), ay = fabsf(y), az = fabsf(z);
    bool is_x = (ax >= ay) && (ax >= az);
    bool is_y = (!is_x) && (ay >= az);
    float ma, sc, tc;
    if (is_x) {
        if (x >= 0.0f) { face = 0; sc = -z; } else { face = 1; sc = z; }
        ma = ax; tc = -y;
    } else if (is_y) {
        if (y >= 0.0f) { face = 2; tc = z; } else { face = 3; tc = -z; }
        ma = ay; sc = x;
    } else {
        if (z >= 0.0f) { face = 4; sc = x; } else { face = 5; sc = -x; }
        ma = az; tc = -y;
    }
    float inv = 1.0f / fmaxf(ma, 1e-12f);
    u = 0.5f * (sc * inv + 1.0f);
    v = 0.5f * (tc * inv + 1.0f);
}

// bucket key: face * 8 + v-slice (approximates bg1 row-region; exactness
// not required — a mis-keyed ray only costs a cross-XCD L2 miss)
__device__ inline int ray_key(float x, float y, float z) {
    int face; float u, v;
    cube_coords(x, y, z, face, u, v);
    int s = min((int)(v * 8.0f), 7);
    return face * 8 + s;
}

// ---------------------------------------------------------------------------
// 8B half4 texels, 2-row-paired tiled layout (bg0p / bg1p):
// float2 element ((face*H/2 + y/2)*W + x)*2 + (y&1)
// ---------------------------------------------------------------------------
struct BLT {
    int i00, i10, i01, i11;
    float wx, wy;
};

__device__ inline BLT bl_tiled(float u, float v, int H, int W, int face) {
    float fx = u * (float)W - 0.5f;
    float fy = v * (float)H - 0.5f;
    float x0 = floorf(fx), y0 = floorf(fy);
    BLT b;
    b.wx = fx - x0;
    b.wy = fy - y0;
    int x0i = min(max((int)x0, 0), W - 1);
    int x1i = min(max((int)x0 + 1, 0), W - 1);
    int y0i = min(max((int)y0, 0), H - 1);
    int y1i = min(max((int)y0 + 1, 0), H - 1);
    int fb = face * (H >> 1);
    int r0 = (fb + (y0i >> 1)) * W;
    int r1 = (fb + (y1i >> 1)) * W;
    b.i00 = (r0 + x0i) * 2 + (y0i & 1);
    b.i10 = (r0 + x1i) * 2 + (y0i & 1);
    b.i01 = (r1 + x0i) * 2 + (y1i & 1);
    b.i11 = (r1 + x1i) * 2 + (y1i & 1);
    return b;
}

__device__ inline void fetch_bl(const float2* __restrict__ tex,
                                const BLT& b, float c[3]) {
    H4U t00, t10, t01, t11;
    t00.f2 = tex[b.i00];
    t10.f2 = tex[b.i10];
    t01.f2 = tex[b.i01];
    t11.f2 = tex[b.i11];
    float wx = b.wx, wy = b.wy;
#pragma unroll
    for (int k = 0; k < 3; ++k) {
        float top = __half2float(t00.h[k]) * (1.0f - wx) + __half2float(t10.h[k]) * wx;
        float bot = __half2float(t01.h[k]) * (1.0f - wx) + __half2float(t11.h[k]) * wx;
        c[k] = top * (1.0f - wy) + bot * wy;
    }
}

// ---------------------------------------------------------------------------
// Interleaved blur records: per 128-map texel, 4 levels x half4 = 32B.
// rec = ((face*64 + y/2)*128 + x)*2 + (y&1)
// ---------------------------------------------------------------------------
struct BLR {
    int r00, r10, r01, r11;
    float wx, wy;
};

__device__ inline BLR bl_rec(float u, float v, int face) {
    float fx = u * 128.0f - 0.5f;
    float fy = v * 128.0f - 0.5f;
    float x0 = floorf(fx), y0 = floorf(fy);
    BLR b;
    b.wx = fx - x0;
    b.wy = fy - y0;
    int x0i = min(max((int)x0, 0), 127);
    int x1i = min(max((int)x0 + 1, 0), 127);
    int y0i = min(max((int)y0, 0), 127);
    int y1i = min(max((int)y0 + 1, 0), 127);
    int fb = face * 64;
    int r0 = (fb + (y0i >> 1)) * 128;
    int r1 = (fb + (y1i >> 1)) * 128;
    b.r00 = (r0 + x0i) * 2 + (y0i & 1);
    b.r10 = (r0 + x1i) * 2 + (y0i & 1);
    b.r01 = (r1 + x0i) * 2 + (y1i & 1);
    b.r11 = (r1 + x1i) * 2 + (y1i & 1);
    return b;
}

__device__ inline void accum_level(const H8U& q00, const H8U& q10,
                                   const H8U& q01, const H8U& q11,
                                   int off, float w, float wx, float wy,
                                   float& b0, float& b1, float& b2) {
    float c[3];
#pragma unroll
    for (int k = 0; k < 3; ++k) {
        float top = __half2float(q00.h[off + k]) * (1.0f - wx) + __half2float(q10.h[off + k]) * wx;
        float bot = __half2float(q01.h[off + k]) * (1.0f - wx) + __half2float(q11.h[off + k]) * wx;
        c[k] = top * (1.0f - wy) + bot * wy;
    }
    b0 += w * c[0];
    b1 += w * c[1];
    b2 += w * c[2];
}

// ---------------------------------------------------------------------------
// Inline f32 Gaussian weights
// ---------------------------------------------------------------------------
__device__ inline void weights_inline(int tid, float wS[4][32]) {
    const float ss[4] = {8.f, 4.f, 2.f, 1.f};
    int lvl = (tid >> 5) & 3;
    int tap = tid & 31;
    float d = (float)tap - 15.0f;
    float q = d / ss[lvl];
    float g = (tap < KSIZE) ? expf(-0.5f * q * q) : 0.0f;
    float s = g;
#pragma unroll
    for (int k = 16; k; k >>= 1) s += __shfl_xor(s, k, 32);
    if (tid < 128) wS[lvl][tap] = g / s;
}

// ---------------------------------------------------------------------------
// Horizontal blur (4 levels) + bg0 tiled-texel emit, fused.
// blockIdx = face*128 + yrow.  tmp: [face][y][x][lvl*3+c] (3 float4/texel)
// ---------------------------------------------------------------------------
__global__ __launch_bounds__(128)
void blur_h4(const float* __restrict__ bg0, float4* __restrict__ tmp,
             float2* __restrict__ bg0p) {
    __shared__ float wS[4][32];
    __shared__ float rowA[128 * 3];
    int bid  = blockIdx.x;
    int yrow = bid & 127;
    int face = bid >> 7;
    int tid  = threadIdx.x;

    weights_inline(tid, wS);
    const float* srcA = bg0 + (size_t)(face * 128 + yrow) * 384;
    for (int k = tid; k < 384; k += 128) rowA[k] = srcA[k];
    __syncthreads();

    int x = tid;
    float a[4][3] = {};
    for (int t = 0; t < KSIZE; ++t) {
        int xx = x + t - HRAD;
        if (xx >= 0 && xx < 128) {
            float r0 = rowA[xx * 3 + 0];
            float r1 = rowA[xx * 3 + 1];
            float r2 = rowA[xx * 3 + 2];
#pragma unroll
            for (int l = 0; l < 4; ++l) {
                float w = wS[l][t];
                a[l][0] += w * r0; a[l][1] += w * r1; a[l][2] += w * r2;
            }
        }
    }
    size_t idx = (size_t)(face * 128 + yrow) * 128 + x;
    tmp[idx * 3 + 0] = make_float4(a[0][0], a[0][1], a[0][2], a[1][0]);
    tmp[idx * 3 + 1] = make_float4(a[1][1], a[1][2], a[2][0], a[2][1]);
    tmp[idx * 3 + 2] = make_float4(a[2][2], a[3][0], a[3][1], a[3][2]);

    // bg0 tiled half4 texel
    H4U t;
    t.h[0] = __float2half(rowA[x * 3 + 0]);
    t.h[1] = __float2half(rowA[x * 3 + 1]);
    t.h[2] = __float2half(rowA[x * 3 + 2]);
    t.h[3] = __float2half(0.0f);
    int idxT = ((face * 64 + (yrow >> 1)) * 128 + x) * 2 + (yrow & 1);
    bg0p[idxT] = t.f2;
}

// ---------------------------------------------------------------------------
// Vertical blur: one output row per block; 3 float4 loads per tap row.
// ---------------------------------------------------------------------------
__global__ __launch_bounds__(128)
void blur_v4(const float4* __restrict__ tmp, float4* __restrict__ blurp) {
    __shared__ float wS[4][32];
    int bid  = blockIdx.x;
    int yrow = bid & 127;
    int face = bid >> 7;
    int tid  = threadIdx.x;

    weights_inline(tid, wS);
    __syncthreads();

    int x = tid;
    float acc[12] = {};
    int ylo = max(yrow - HRAD, 0);
    int yhi = min(yrow + HRAD, 127);
    for (int yy = ylo; yy <= yhi; ++yy) {
        int t = yy - yrow + HRAD;
        size_t idx = (size_t)(face * 128 + yy) * 128 + x;
        float4 q0 = tmp[idx * 3 + 0];
        float4 q1 = tmp[idx * 3 + 1];
        float4 q2 = tmp[idx * 3 + 2];
        float w0 = wS[0][t], w1 = wS[1][t], w2 = wS[2][t], w3 = wS[3][t];
        acc[0]  += w0 * q0.x; acc[1]  += w0 * q0.y; acc[2]  += w0 * q0.z;
        acc[3]  += w1 * q0.w; acc[4]  += w1 * q1.x; acc[5]  += w1 * q1.y;
        acc[6]  += w2 * q1.z; acc[7]  += w2 * q1.w; acc[8]  += w2 * q2.x;
        acc[9]  += w3 * q2.y; acc[10] += w3 * q2.z; acc[11] += w3 * q2.w;
    }

    H8U ra, rb;
#pragma unroll
    for (int l = 0; l < 2; ++l) {
        ra.h[l * 4 + 0] = __float2half(acc[l * 3 + 0]);
        ra.h[l * 4 + 1] = __float2half(acc[l * 3 + 1]);
        ra.h[l * 4 + 2] = __float2half(acc[l * 3 + 2]);
        ra.h[l * 4 + 3] = __float2half(0.0f);
        rb.h[l * 4 + 0] = __float2half(acc[6 + l * 3 + 0]);
        rb.h[l * 4 + 1] = __float2half(acc[6 + l * 3 + 1]);
        rb.h[l * 4 + 2] = __float2half(acc[6 + l * 3 + 2]);
        rb.h[l * 4 + 3] = __float2half(0.0f);
    }
    int rec = ((face * 64 + (yrow >> 1)) * 128 + x) * 2 + (yrow & 1);
    blurp[(size_t)rec * 2 + 0] = ra.f4;
    blurp[(size_t)rec * 2 + 1] = rb.f4;
}

// ---------------------------------------------------------------------------
// Pack bg1: f32 RGB -> 8B half4 tiled (12.6 MB)
// ---------------------------------------------------------------------------
__global__ __launch_bounds__(256)
void pack_tiled(const float* __restrict__ src, float2* __restrict__ dst,
                int H, int W, int total) {
    int i = blockIdx.x * blockDim.x + threadIdx.x;
    if (i >= total) return;
    int x = i % W;
    int y = (i / W) % H;
    int f = i / (W * H);
    H4U u;
    u.h[0] = __float2half(src[(size_t)i * 3 + 0]);
    u.h[1] = __float2half(src[(size_t)i * 3 + 1]);
    u.h[2] = __float2half(src[(size_t)i * 3 + 2]);
    u.h[3] = __float2half(0.0f);
    int idx = ((f * (H >> 1) + (y >> 1)) * W + x) * 2 + (y & 1);
    dst[idx] = u.f2;
}

// ---------------------------------------------------------------------------
// Per-ray shading (identical math to proven rounds)
// ---------------------------------------------------------------------------
__device__ inline void shade_ray(float x, float y, float z, float sa,
                                 const float2* __restrict__ bg0p,
                                 const float2* __restrict__ bg1p,
                                 const float4* __restrict__ blurp,
                                 float R[3]) {
    int face; float u, v;
    cube_coords(x, y, z, face, u, v);

    const float saTexel = (float)(4.0 * M_PI / (6.0 * 512.0 * 512.0));
    float m = logf(sa / saTexel);
    m = m / 1.3862943611198906f;   // f32(log(4))
    m = m * 0.5f;
    m = fminf(fmaxf(m, 0.0f), 3.0f);

    if (m >= 2.0f) {
        BLR b = bl_rec(u, v, face);
        H8U q00a, q00b, q10a, q10b, q01a, q01b, q11a, q11b;
        q00a.f4 = blurp[b.r00 * 2 + 0]; q00b.f4 = blurp[b.r00 * 2 + 1];
        q10a.f4 = blurp[b.r10 * 2 + 0]; q10b.f4 = blurp[b.r10 * 2 + 1];
        q01a.f4 = blurp[b.r01 * 2 + 0]; q01b.f4 = blurp[b.r01 * 2 + 1];
        q11a.f4 = blurp[b.r11 * 2 + 0]; q11b.f4 = blurp[b.r11 * 2 + 1];

        float w0 = 1.0f - fminf(fabsf(3.0f - m), 1.0f);
        float w1 = 1.0f - fminf(fabsf(2.5f - m), 1.0f);
        float w2 = 1.0f - fminf(fabsf(2.0f - m), 1.0f);
        float w3 = 1.0f - fminf(fabsf(1.5f - m), 1.0f);

        float b0 = 0.f, b1 = 0.f, b2 = 0.f;
        accum_level(q00a, q10a, q01a, q11a, 0, w0, b.wx, b.wy, b0, b1, b2);
        accum_level(q00a, q10a, q01a, q11a, 4, w1, b.wx, b.wy, b0, b1, b2);
        accum_level(q00b, q10b, q01b, q11b, 0, w2, b.wx, b.wy, b0, b1, b2);
        accum_level(q00b, q10b, q01b, q11b, 4, w3, b.wx, b.wy, b0, b1, b2);

        float denom = fmaxf(w0 + w1 + w2 + w3, 1e-8f);
        R[0] = b0 / denom; R[1] = b1 / denom; R[2] = b2 / denom;
    } else {
        BLT b128 = bl_tiled(u, v, 128, 128, face);
        BLT b512 = bl_tiled(u, v, 512, 512, face);
        float c0[3], c1[3];
        fetch_bl(bg0p, b128, c0);
        fetch_bl(bg1p, b512, c1);
        R[0] = c0[0] + 0.5f * c1[0];
        R[1] = c0[1] + 0.5f * c1[1];
        R[2] = c0[2] + 0.5f * c1[2];
    }
}

// ---------------------------------------------------------------------------
// Sorting pipeline
// ---------------------------------------------------------------------------
__global__ __launch_bounds__(64)
void init_counts(int* __restrict__ counts) {
    if (threadIdx.x < NBUCK) counts[threadIdx.x] = 0;
}

// 2048 rays per block (8/thread); qoff = first quad of this batch
__global__ __launch_bounds__(256)
void count_keys(const float4* __restrict__ vd4, int* __restrict__ counts,
                int qoff) {
    __shared__ int h[NBUCK];
    int tid = threadIdx.x;
    if (tid < NBUCK) h[tid] = 0;
    __syncthreads();
    int qbase = qoff + blockIdx.x * 512;
#pragma unroll
    for (int g = 0; g < 2; ++g) {
        int q = qbase + g * 256 + tid;
        float4 a = vd4[3 * q + 0];
        float4 b = vd4[3 * q + 1];
        float4 c = vd4[3 * q + 2];
        float X[4] = {a.x, a.w, b.z, c.y};
        float Y[4] = {a.y, b.x, b.w, c.z};
        float Z[4] = {a.z, b.y, c.x, c.w};
#pragma unroll
        for (int r = 0; r < 4; ++r)
            atomicAdd(&h[ray_key(X[r], Y[r], Z[r])], 1);
    }
    __syncthreads();
    if (tid < NBUCK) atomicAdd(&counts[tid], h[tid]);
}

__global__ __launch_bounds__(64)
void prefix48(const int* __restrict__ counts, int* __restrict__ starts,
              int* __restrict__ cursors) {
    if (threadIdx.x == 0) {
        int acc = 0;
        for (int k = 0; k < NBUCK; ++k) {
            starts[k] = acc; cursors[k] = acc; acc += counts[k];
        }
    }
}

__global__ __launch_bounds__(256)
void scatter_rays(const float4* __restrict__ vd4, const float4* __restrict__ sa4,
                  int* __restrict__ cursors,
                  float4* __restrict__ sdata, int* __restrict__ sidx,
                  int qoff) {
    __shared__ int h[NBUCK];
    __shared__ int base[NBUCK];
    __shared__ int rk[NBUCK];
    int tid = threadIdx.x;
    if (tid < NBUCK) { h[tid] = 0; rk[tid] = 0; }
    __syncthreads();
    int qbase = qoff + blockIdx.x * 512;

    float X[8], Y[8], Z[8], S[8];
    int K[8];
#pragma unroll
    for (int g = 0; g < 2; ++g) {
        int q = qbase + g * 256 + tid;
        float4 a  = vd4[3 * q + 0];
        float4 b  = vd4[3 * q + 1];
        float4 c  = vd4[3 * q + 2];
        float4 s4 = sa4[q];
        float xs[4] = {a.x, a.w, b.z, c.y};
        float ys[4] = {a.y, b.x, b.w, c.z};
        float zs[4] = {a.z, b.y, c.x, c.w};
        float ss[4] = {s4.x, s4.y, s4.z, s4.w};
#pragma unroll
        for (int r = 0; r < 4; ++r) {
            int j = g * 4 + r;
            X[j] = xs[r]; Y[j] = ys[r]; Z[j] = zs[r]; S[j] = ss[r];
            K[j] = ray_key(xs[r], ys[r], zs[r]);
            atomicAdd(&h[K[j]], 1);
        }
    }
    __syncthreads();
    if (tid < NBUCK) base[tid] = atomicAdd(&cursors[tid], h[tid]);
    __syncthreads();
#pragma unroll
    for (int g = 0; g < 2; ++g) {
#pragma unroll
        for (int r = 0; r < 4; ++r) {
            int j = g * 4 + r;
            int p = base[K[j]] + atomicAdd(&rk[K[j]], 1);
            sdata[p] = make_float4(X[j], Y[j], Z[j], S[j]);
            sidx[p]  = (qbase + g * 256 + tid) * 4 + r;
        }
    }
}

// 4080 blocks: block b -> bucket k = b%48 (k%8 == b%8 -> XCD-local), sub = b/48
__global__ __launch_bounds__(256)
void shade_sorted(const float4* __restrict__ sdata, const int* __restrict__ sidx,
                  const int* __restrict__ starts, const int* __restrict__ counts,
                  const float2* __restrict__ bg0p, const float2* __restrict__ bg1p,
                  const float4* __restrict__ blurp, float* __restrict__ out) {
    int b = blockIdx.x;
    int k = b % NBUCK;
    int sub = b / NBUCK;
    int s = starts[k], n = counts[k];
    for (int i = s + sub * 256 + (int)threadIdx.x; i < s + n; i += 85 * 256) {
        float4 d = sdata[i];
        int idx = sidx[i];
        float R[3];
        shade_ray(d.x, d.y, d.z, d.w, bg0p, bg1p, blurp, R);
        out[idx * 3 + 0] = R[0];
        out[idx * 3 + 1] = R[1];
        out[idx * 3 + 2] = R[2];
    }
}

// ---------------------------------------------------------------------------
// Fallback: unsorted shade, 4 rays/thread
// ---------------------------------------------------------------------------
__global__ __launch_bounds__(256)
void shade_unsorted(const float4* __restrict__ vd4, const float4* __restrict__ sa4,
                    const float2* __restrict__ bg0p, const float2* __restrict__ bg1p,
                    const float4* __restrict__ blurp, float4* __restrict__ out4,
                    int nquads) {
    int q = blockIdx.x * blockDim.x + threadIdx.x;
    if (q >= nquads) return;
    float4 a = vd4[3 * q + 0];
    float4 b = vd4[3 * q + 1];
    float4 c = vd4[3 * q + 2];
    float4 s = sa4[q];
    float X[4] = {a.x, a.w, b.z, c.y};
    float Y[4] = {a.y, b.x, b.w, c.z};
    float Z[4] = {a.z, b.y, c.x, c.w};
    float S[4] = {s.x, s.y, s.z, s.w};
    float R[12];
#pragma unroll
    for (int r = 0; r < 4; ++r)
        shade_ray(X[r], Y[r], Z[r], S[r], bg0p, bg1p, blurp, &R[3 * r]);
    out4[3 * q + 0] = make_float4(R[0], R[1], R[2],  R[3]);
    out4[3 * q + 1] = make_float4(R[4], R[5], R[6],  R[7]);
    out4[3 * q + 2] = make_float4(R[8], R[9], R[10], R[11]);
}

// ---------------------------------------------------------------------------
extern "C" void kernel_launch(void* const* d_in, const int* in_sizes, int n_in,
                              void* d_out, int out_size, void* d_ws, size_t ws_size,
                              hipStream_t stream) {
    const float* viewdirs = (const float*)d_in[0];   // (B,3)
    const float* saSample = (const float*)d_in[1];   // (B,1)
    const float* bg0      = (const float*)d_in[2];   // (6,128,128,3)
    const float* bg1      = (const float*)d_in[3];   // (6,512,512,3)
    float* out = (float*)d_out;

    int B = in_sizes[0] / 3;          // 2097152
    int nquads = B / 4;               // 524288

    // ws layout (float4 units):
    //   blurp 196608 | bg0p 49152 (as f2: 98304) | bg1p 393216 (f2: 786432... bytes below)
    // bytes: blurp 3,145,728 | bg0p 786,432 | bg1p 12,582,912 | tex subtotal 16,515,072
    // sorted tiers add: sdata batchRays*16 + sidx batchRays*4 + ctrl 768
    float4* blurp = (float4*)d_ws;
    float2* bg0p  = (float2*)(blurp + 196608);
    float2* bg1p  = bg0p + 98304;
    float4* texEnd = (float4*)(bg1p + 1572864);
    // tmp (9.4 MB) aliases bg1p region head in unsorted mode is NOT possible
    // (bg1p is 12.6 MB and packed after blur) -> alias tmp over sdata region
    // when sorted; in unsorted mode alias over bg1p (pack runs after blur_v4).
    const size_t TEX_BYTES = 16515072;

    // pick batching tier
    int nbatch = 0;  // 0 = unsorted
    size_t need1 = TEX_BYTES + (size_t)B * 20 + 768;
    size_t need2 = TEX_BYTES + (size_t)(B / 2) * 20 + 768;
    size_t need4 = TEX_BYTES + (size_t)(B / 4) * 20 + 768;
    if      (ws_size >= need1) nbatch = 1;
    else if (ws_size >= need2) nbatch = 2;
    else if (ws_size >= need4) nbatch = 4;

    int batchRays = nbatch ? B / nbatch : 0;
    float4* sdata = texEnd;
    int*    sidx  = (int*)(sdata + (nbatch ? batchRays : 0));
    int*    counts  = nbatch ? sidx + batchRays : nullptr;
    int*    starts  = nbatch ? counts + 64 : nullptr;
    int*    cursors = nbatch ? starts + 64 : nullptr;

    float4* tmp = nbatch ? texEnd : (float4*)bg1p;  // 9.4 MB scratch

    blur_h4<<<6 * 128, 128, 0, stream>>>(bg0, tmp, bg0p);
    blur_v4<<<6 * 128, 128, 0, stream>>>(tmp, blurp);
    int t1 = 6 * 512 * 512;
    pack_tiled<<<(t1 + 255) / 256, 256, 0, stream>>>(bg1, bg1p, 512, 512, t1);

    if (nbatch) {
        int batchQuads = batchRays / 4;
        int ablocks = batchRays / 2048;
        for (int bt = 0; bt < nbatch; ++bt) {
            int qoff = bt * batchQuads;
            init_counts<<<1, 64, 0, stream>>>(counts);
            count_keys<<<ablocks, 256, 0, stream>>>((const float4*)viewdirs,
                                                    counts, qoff);
            prefix48<<<1, 64, 0, stream>>>(counts, starts, cursors);
            scatter_rays<<<ablocks, 256, 0, stream>>>((const float4*)viewdirs,
                                                      (const float4*)saSample,
                                                      cursors, sdata, sidx, qoff);
            shade_sorted<<<NBUCK * 85, 256, 0, stream>>>(sdata, sidx, starts,
                                                         counts, bg0p, bg1p,
                                                         blurp, out);
        }
    } else {
        int blocks = (nquads + 255) / 256;
        shade_unsorted<<<blocks, 256, 0, stream>>>((const float4*)viewdirs,
                                                   (const float4*)saSample,
                                                   bg0p, bg1p, blurp,
                                                   (float4*)out, nquads);
    }
}

// Round 8
// 112.128 us; speedup vs baseline: 1.3684x; 1.3684x over previous
//
#include <hip/hip_runtime.h>
#include <hip/hip_fp16.h>
#include <math.h>

#define KSIZE 31
#define HRAD 15

union H4U { float2 f2; __half h[4]; };
union H8U { float4 f4; __half h[8]; };

// ---------------------------------------------------------------------------
// Cube-map coordinate math (mirrors reference cube_sample exactly, f32)
// ---------------------------------------------------------------------------
__device__ inline void cube_coords(float x, float y, float z,
                                   int& face, float& u, float& v) {
    float ax = fabsf(x), ay = fabsf(y), az = fabsf(z);
    bool is_x = (ax >= ay) && (ax >= az);
    bool is_y = (!is_x) && (ay >= az);
    float ma, sc, tc;
    if (is_x) {
        if (x >= 0.0f) { face = 0; sc = -z; } else { face = 1; sc = z; }
        ma = ax; tc = -y;
    } else if (is_y) {
        if (y >= 0.0f) { face = 2; tc = z; } else { face = 3; tc = -z; }
        ma = ay; sc = x;
    } else {
        if (z >= 0.0f) { face = 4; sc = x; } else { face = 5; sc = -x; }
        ma = az; tc = -y;
    }
    float inv = 1.0f / fmaxf(ma, 1e-12f);
    u = 0.5f * (sc * inv + 1.0f);
    v = 0.5f * (tc * inv + 1.0f);
}

// ---------------------------------------------------------------------------
// bg0 neighborhood records: per texel (x,y), 32B = 4 half4 corners
// rec = (face*128 + y)*128 + x ; corners clamped at build; left/top edge
// handled by forcing wx/wy = 0 (exact).
// ---------------------------------------------------------------------------
__device__ inline void nb_setup(float u, float v, int HW, int face,
                                int& rec, float& wx, float& wy) {
    float fx = u * (float)HW - 0.5f;
    float fy = v * (float)HW - 0.5f;
    float x0 = floorf(fx), y0 = floorf(fy);
    wx = fx - x0;
    wy = fy - y0;
    int xi = (int)x0, yi = (int)y0;
    if (xi < 0) { xi = 0; wx = 0.0f; }
    if (yi < 0) { yi = 0; wy = 0.0f; }
    rec = (face * HW + yi) * HW + xi;
}

__device__ inline void nb_fetch(const float4* __restrict__ nb, int rec,
                                float wx, float wy, float c[3]) {
    H8U qa, qb;
    qa.f4 = nb[(size_t)rec * 2 + 0];
    qb.f4 = nb[(size_t)rec * 2 + 1];
#pragma unroll
    for (int k = 0; k < 3; ++k) {
        float top = __half2float(qa.h[k]) * (1.0f - wx) + __half2float(qa.h[4 + k]) * wx;
        float bot = __half2float(qb.h[k]) * (1.0f - wx) + __half2float(qb.h[4 + k]) * wx;
        c[k] = top * (1.0f - wy) + bot * wy;
    }
}

// ---------------------------------------------------------------------------
// 8B half4 texels, 2-row-paired tiled layout (bg1p):
// float2 element ((face*H/2 + y/2)*W + x)*2 + (y&1)
// ---------------------------------------------------------------------------
struct BLT {
    int i00, i10, i01, i11;
    float wx, wy;
};

__device__ inline BLT bl_tiled(float u, float v, int H, int W, int face) {
    float fx = u * (float)W - 0.5f;
    float fy = v * (float)H - 0.5f;
    float x0 = floorf(fx), y0 = floorf(fy);
    BLT b;
    b.wx = fx - x0;
    b.wy = fy - y0;
    int x0i = min(max((int)x0, 0), W - 1);
    int x1i = min(max((int)x0 + 1, 0), W - 1);
    int y0i = min(max((int)y0, 0), H - 1);
    int y1i = min(max((int)y0 + 1, 0), H - 1);
    int fb = face * (H >> 1);
    int r0 = (fb + (y0i >> 1)) * W;
    int r1 = (fb + (y1i >> 1)) * W;
    b.i00 = (r0 + x0i) * 2 + (y0i & 1);
    b.i10 = (r0 + x1i) * 2 + (y0i & 1);
    b.i01 = (r1 + x0i) * 2 + (y1i & 1);
    b.i11 = (r1 + x1i) * 2 + (y1i & 1);
    return b;
}

__device__ inline void fetch_bl(const float2* __restrict__ tex,
                                const BLT& b, float c[3]) {
    H4U t00, t10, t01, t11;
    t00.f2 = tex[b.i00];
    t10.f2 = tex[b.i10];
    t01.f2 = tex[b.i01];
    t11.f2 = tex[b.i11];
    float wx = b.wx, wy = b.wy;
#pragma unroll
    for (int k = 0; k < 3; ++k) {
        float top = __half2float(t00.h[k]) * (1.0f - wx) + __half2float(t10.h[k]) * wx;
        float bot = __half2float(t01.h[k]) * (1.0f - wx) + __half2float(t11.h[k]) * wx;
        c[k] = top * (1.0f - wy) + bot * wy;
    }
}

// ---------------------------------------------------------------------------
// Interleaved blur records: per 128-map texel, 4 levels x half4 = 32B.
// rec = ((face*64 + y/2)*128 + x)*2 + (y&1)
// ---------------------------------------------------------------------------
struct BLR {
    int r00, r10, r01, r11;
    float wx, wy;
};

__device__ inline BLR bl_rec(float u, float v, int face) {
    float fx = u * 128.0f - 0.5f;
    float fy = v * 128.0f - 0.5f;
    float x0 = floorf(fx), y0 = floorf(fy);
    BLR b;
    b.wx = fx - x0;
    b.wy = fy - y0;
    int x0i = min(max((int)x0, 0), 127);
    int x1i = min(max((int)x0 + 1, 0), 127);
    int y0i = min(max((int)y0, 0), 127);
    int y1i = min(max((int)y0 + 1, 0), 127);
    int fb = face * 64;
    int r0 = (fb + (y0i >> 1)) * 128;
    int r1 = (fb + (y1i >> 1)) * 128;
    b.r00 = (r0 + x0i) * 2 + (y0i & 1);
    b.r10 = (r0 + x1i) * 2 + (y0i & 1);
    b.r01 = (r1 + x0i) * 2 + (y1i & 1);
    b.r11 = (r1 + x1i) * 2 + (y1i & 1);
    return b;
}

__device__ inline void accum_level(const H8U& q00, const H8U& q10,
                                   const H8U& q01, const H8U& q11,
                                   int off, float w, float wx, float wy,
                                   float& b0, float& b1, float& b2) {
    float c[3];
#pragma unroll
    for (int k = 0; k < 3; ++k) {
        float top = __half2float(q00.h[off + k]) * (1.0f - wx) + __half2float(q10.h[off + k]) * wx;
        float bot = __half2float(q01.h[off + k]) * (1.0f - wx) + __half2float(q11.h[off + k]) * wx;
        c[k] = top * (1.0f - wy) + bot * wy;
    }
    b0 += w * c[0];
    b1 += w * c[1];
    b2 += w * c[2];
}

// ---------------------------------------------------------------------------
// Inline f32 Gaussian weights
// ---------------------------------------------------------------------------
__device__ inline void weights_inline(int tid, float wS[4][32]) {
    const float ss[4] = {8.f, 4.f, 2.f, 1.f};
    int lvl = (tid >> 5) & 3;
    int tap = tid & 31;
    float d = (float)tap - 15.0f;
    float q = d / ss[lvl];
    float g = (tap < KSIZE) ? expf(-0.5f * q * q) : 0.0f;
    float s = g;
#pragma unroll
    for (int k = 16; k; k >>= 1) s += __shfl_xor(s, k, 32);
    if (tid < 128) wS[lvl][tap] = g / s;
}

// ---------------------------------------------------------------------------
// Horizontal blur (4 levels) + bg0 neighborhood-record emit, fused.
// blockIdx = face*128 + yrow.  tmp: [face][y][x][lvl*3+c] (3 float4/texel)
// ---------------------------------------------------------------------------
__global__ __launch_bounds__(128)
void blur_h4(const float* __restrict__ bg0, float4* __restrict__ tmp,
             float4* __restrict__ bg0n) {
    __shared__ float wS[4][32];
    __shared__ float rowA[128 * 3];
    __shared__ float rowB[128 * 3];
    int bid  = blockIdx.x;
    int yrow = bid & 127;
    int face = bid >> 7;
    int tid  = threadIdx.x;

    weights_inline(tid, wS);
    int ynext = min(yrow + 1, 127);
    const float* srcA = bg0 + (size_t)(face * 128 + yrow) * 384;
    const float* srcB = bg0 + (size_t)(face * 128 + ynext) * 384;
    for (int k = tid; k < 384; k += 128) { rowA[k] = srcA[k]; rowB[k] = srcB[k]; }
    __syncthreads();

    int x = tid;
    float a[4][3] = {};
    for (int t = 0; t < KSIZE; ++t) {
        int xx = x + t - HRAD;
        if (xx >= 0 && xx < 128) {
            float r0 = rowA[xx * 3 + 0];
            float r1 = rowA[xx * 3 + 1];
            float r2 = rowA[xx * 3 + 2];
#pragma unroll
            for (int l = 0; l < 4; ++l) {
                float w = wS[l][t];
                a[l][0] += w * r0; a[l][1] += w * r1; a[l][2] += w * r2;
            }
        }
    }
    size_t idx = (size_t)(face * 128 + yrow) * 128 + x;
    tmp[idx * 3 + 0] = make_float4(a[0][0], a[0][1], a[0][2], a[1][0]);
    tmp[idx * 3 + 1] = make_float4(a[1][1], a[1][2], a[2][0], a[2][1]);
    tmp[idx * 3 + 2] = make_float4(a[2][2], a[3][0], a[3][1], a[3][2]);

    // bg0 neighborhood record for (x, yrow)
    int x1 = min(x + 1, 127);
    H8U qa, qb;
#pragma unroll
    for (int k = 0; k < 3; ++k) {
        qa.h[k]     = __float2half(rowA[x * 3 + k]);
        qa.h[4 + k] = __float2half(rowA[x1 * 3 + k]);
        qb.h[k]     = __float2half(rowB[x * 3 + k]);
        qb.h[4 + k] = __float2half(rowB[x1 * 3 + k]);
    }
    qa.h[3] = __float2half(0.0f); qa.h[7] = __float2half(0.0f);
    qb.h[3] = __float2half(0.0f); qb.h[7] = __float2half(0.0f);
    bg0n[idx * 2 + 0] = qa.f4;
    bg0n[idx * 2 + 1] = qb.f4;
}

// ---------------------------------------------------------------------------
// Vertical blur: one output row per block; 3 float4 loads per tap row.
// ---------------------------------------------------------------------------
__global__ __launch_bounds__(128)
void blur_v4(const float4* __restrict__ tmp, float4* __restrict__ blurp) {
    __shared__ float wS[4][32];
    int bid  = blockIdx.x;
    int yrow = bid & 127;
    int face = bid >> 7;
    int tid  = threadIdx.x;

    weights_inline(tid, wS);
    __syncthreads();

    int x = tid;
    float acc[12] = {};
    int ylo = max(yrow - HRAD, 0);
    int yhi = min(yrow + HRAD, 127);
    for (int yy = ylo; yy <= yhi; ++yy) {
        int t = yy - yrow + HRAD;
        size_t idx = (size_t)(face * 128 + yy) * 128 + x;
        float4 q0 = tmp[idx * 3 + 0];
        float4 q1 = tmp[idx * 3 + 1];
        float4 q2 = tmp[idx * 3 + 2];
        float w0 = wS[0][t], w1 = wS[1][t], w2 = wS[2][t], w3 = wS[3][t];
        acc[0]  += w0 * q0.x; acc[1]  += w0 * q0.y; acc[2]  += w0 * q0.z;
        acc[3]  += w1 * q0.w; acc[4]  += w1 * q1.x; acc[5]  += w1 * q1.y;
        acc[6]  += w2 * q1.z; acc[7]  += w2 * q1.w; acc[8]  += w2 * q2.x;
        acc[9]  += w3 * q2.y; acc[10] += w3 * q2.z; acc[11] += w3 * q2.w;
    }

    H8U ra, rb;
#pragma unroll
    for (int l = 0; l < 2; ++l) {
        ra.h[l * 4 + 0] = __float2half(acc[l * 3 + 0]);
        ra.h[l * 4 + 1] = __float2half(acc[l * 3 + 1]);
        ra.h[l * 4 + 2] = __float2half(acc[l * 3 + 2]);
        ra.h[l * 4 + 3] = __float2half(0.0f);
        rb.h[l * 4 + 0] = __float2half(acc[6 + l * 3 + 0]);
        rb.h[l * 4 + 1] = __float2half(acc[6 + l * 3 + 1]);
        rb.h[l * 4 + 2] = __float2half(acc[6 + l * 3 + 2]);
        rb.h[l * 4 + 3] = __float2half(0.0f);
    }
    int rec = ((face * 64 + (yrow >> 1)) * 128 + x) * 2 + (yrow & 1);
    blurp[(size_t)rec * 2 + 0] = ra.f4;
    blurp[(size_t)rec * 2 + 1] = rb.f4;
}

// ---------------------------------------------------------------------------
// Pack bg1: f32 RGB -> 8B half4 tiled (12.6 MB)
// ---------------------------------------------------------------------------
__global__ __launch_bounds__(256)
void pack_tiled(const float* __restrict__ src, float2* __restrict__ dst,
                int H, int W, int total) {
    int i = blockIdx.x * blockDim.x + threadIdx.x;
    if (i >= total) return;
    int x = i % W;
    int y = (i / W) % H;
    int f = i / (W * H);
    H4U u;
    u.h[0] = __float2half(src[(size_t)i * 3 + 0]);
    u.h[1] = __float2half(src[(size_t)i * 3 + 1]);
    u.h[2] = __float2half(src[(size_t)i * 3 + 2]);
    u.h[3] = __float2half(0.0f);
    int idx = ((f * (H >> 1) + (y >> 1)) * W + x) * 2 + (y & 1);
    dst[idx] = u.f2;
}

// ---------------------------------------------------------------------------
// Per-ray shading
// ---------------------------------------------------------------------------
__device__ inline void shade_ray(float x, float y, float z, float sa,
                                 const float4* __restrict__ bg0n,
                                 const float2* __restrict__ bg1p,
                                 const float4* __restrict__ blurp,
                                 float R[3]) {
    int face; float u, v;
    cube_coords(x, y, z, face, u, v);

    const float saTexel = (float)(4.0 * M_PI / (6.0 * 512.0 * 512.0));
    float m = logf(sa / saTexel);
    m = m / 1.3862943611198906f;   // f32(log(4))
    m = m * 0.5f;
    m = fminf(fmaxf(m, 0.0f), 3.0f);

    if (m >= 2.0f) {
        BLR b = bl_rec(u, v, face);
        H8U q00a, q00b, q10a, q10b, q01a, q01b, q11a, q11b;
        q00a.f4 = blurp[b.r00 * 2 + 0]; q00b.f4 = blurp[b.r00 * 2 + 1];
        q10a.f4 = blurp[b.r10 * 2 + 0]; q10b.f4 = blurp[b.r10 * 2 + 1];
        q01a.f4 = blurp[b.r01 * 2 + 0]; q01b.f4 = blurp[b.r01 * 2 + 1];
        q11a.f4 = blurp[b.r11 * 2 + 0]; q11b.f4 = blurp[b.r11 * 2 + 1];

        float w0 = 1.0f - fminf(fabsf(3.0f - m), 1.0f);
        float w1 = 1.0f - fminf(fabsf(2.5f - m), 1.0f);
        float w2 = 1.0f - fminf(fabsf(2.0f - m), 1.0f);
        float w3 = 1.0f - fminf(fabsf(1.5f - m), 1.0f);

        float b0 = 0.f, b1 = 0.f, b2 = 0.f;
        accum_level(q00a, q10a, q01a, q11a, 0, w0, b.wx, b.wy, b0, b1, b2);
        accum_level(q00a, q10a, q01a, q11a, 4, w1, b.wx, b.wy, b0, b1, b2);
        accum_level(q00b, q10b, q01b, q11b, 0, w2, b.wx, b.wy, b0, b1, b2);
        accum_level(q00b, q10b, q01b, q11b, 4, w3, b.wx, b.wy, b0, b1, b2);

        float denom = fmaxf(w0 + w1 + w2 + w3, 1e-8f);
        R[0] = b0 / denom; R[1] = b1 / denom; R[2] = b2 / denom;
    } else {
        int r0i; float wx0, wy0;
        nb_setup(u, v, 128, face, r0i, wx0, wy0);
        BLT b512 = bl_tiled(u, v, 512, 512, face);
        float c0[3], c1[3];
        nb_fetch(bg0n, r0i, wx0, wy0, c0);
        fetch_bl(bg1p, b512, c1);
        R[0] = c0[0] + 0.5f * c1[0];
        R[1] = c0[1] + 0.5f * c1[1];
        R[2] = c0[2] + 0.5f * c1[2];
    }
}

// ---------------------------------------------------------------------------
// Shade: 2 rays per thread, float2 stream I/O.
// ---------------------------------------------------------------------------
__global__ __launch_bounds__(256)
void shade2(const float2* __restrict__ vd2, const float2* __restrict__ sa2,
            const float4* __restrict__ bg0n, const float2* __restrict__ bg1p,
            const float4* __restrict__ blurp, float2* __restrict__ out2,
            int npairs) {
    int q = blockIdx.x * blockDim.x + threadIdx.x;
    if (q >= npairs) return;

    float2 a = vd2[3 * q + 0];
    float2 b = vd2[3 * q + 1];
    float2 c = vd2[3 * q + 2];
    float2 s = sa2[q];

    float R0[3], R1[3];
    shade_ray(a.x, a.y, b.x, s.x, bg0n, bg1p, blurp, R0);
    shade_ray(b.y, c.x, c.y, s.y, bg0n, bg1p, blurp, R1);

    out2[3 * q + 0] = make_float2(R0[0], R0[1]);
    out2[3 * q + 1] = make_float2(R0[2], R1[0]);
    out2[3 * q + 2] = make_float2(R1[1], R1[2]);
}

// ---------------------------------------------------------------------------
extern "C" void kernel_launch(void* const* d_in, const int* in_sizes, int n_in,
                              void* d_out, int out_size, void* d_ws, size_t ws_size,
                              hipStream_t stream) {
    const float* viewdirs = (const float*)d_in[0];   // (B,3)
    const float* saSample = (const float*)d_in[1];   // (B,1)
    const float* bg0      = (const float*)d_in[2];   // (6,128,128,3)
    const float* bg1      = (const float*)d_in[3];   // (6,512,512,3)
    float* out = (float*)d_out;

    int B = in_sizes[0] / 3;          // 2097152

    // ws layout (28.4 MB total):
    //   blurp : 196608 float4  (3.0 MB)
    //   bg0n  : 196608 float4  (3.0 MB)   98304 records x 32B
    //   bg1p  : 1572864 float2 (12.6 MB)
    //   tmp   : 589824 float4  (9.4 MB)
    float4* blurp = (float4*)d_ws;
    float4* bg0n  = blurp + 196608;
    float2* bg1p  = (float2*)(bg0n + 196608);
    float4* tmp   = (float4*)(bg1p + 1572864);

    blur_h4<<<6 * 128, 128, 0, stream>>>(bg0, tmp, bg0n);
    blur_v4<<<6 * 128, 128, 0, stream>>>(tmp, blurp);
    int t1 = 6 * 512 * 512;
    pack_tiled<<<(t1 + 255) / 256, 256, 0, stream>>>(bg1, bg1p, 512, 512, t1);

    int npairs = B / 2;               // 1048576
    int blocks = npairs / 256;        // 4096
    shade2<<<blocks, 256, 0, stream>>>((const float2*)viewdirs,
                                       (const float2*)saSample,
                                       bg0n, bg1p, blurp,
                                       (float2*)out, npairs);
}

// Round 9
// 104.043 us; speedup vs baseline: 1.4747x; 1.0777x over previous
//
#include <hip/hip_runtime.h>
#include <hip/hip_fp16.h>
#include <math.h>

#define KSIZE 31
#define HRAD 15

union H4U { float2 f2; __half h[4]; };
union H8U { float4 f4; __half h[8]; };

// ---------------------------------------------------------------------------
// Cube-map coordinate math (mirrors reference cube_sample exactly, f32)
// ---------------------------------------------------------------------------
__device__ inline void cube_coords(float x, float y, float z,
                                   int& face, float& u, float& v) {
    float ax = fabsf(x), ay = fabsf(y), az = fabsf(z);
    bool is_x = (ax >= ay) && (ax >= az);
    bool is_y = (!is_x) && (ay >= az);
    float ma, sc, tc;
    if (is_x) {
        if (x >= 0.0f) { face = 0; sc = -z; } else { face = 1; sc = z; }
        ma = ax; tc = -y;
    } else if (is_y) {
        if (y >= 0.0f) { face = 2; tc = z; } else { face = 3; tc = -z; }
        ma = ay; sc = x;
    } else {
        if (z >= 0.0f) { face = 4; sc = x; } else { face = 5; sc = -x; }
        ma = az; tc = -y;
    }
    float inv = 1.0f / fmaxf(ma, 1e-12f);
    u = 0.5f * (sc * inv + 1.0f);
    v = 0.5f * (tc * inv + 1.0f);
}

// ---------------------------------------------------------------------------
// Neighborhood records: per texel (x,y), 32B = 4 half4 corners
// rec = (face*HW + y)*HW + x ; corners clamped at build; left/top edge
// handled by forcing wx/wy = 0 (exact).
// ---------------------------------------------------------------------------
__device__ inline void nb_setup(float u, float v, int HW, int face,
                                int& rec, float& wx, float& wy) {
    float fx = u * (float)HW - 0.5f;
    float fy = v * (float)HW - 0.5f;
    float x0 = floorf(fx), y0 = floorf(fy);
    wx = fx - x0;
    wy = fy - y0;
    int xi = (int)x0, yi = (int)y0;
    if (xi < 0) { xi = 0; wx = 0.0f; }
    if (yi < 0) { yi = 0; wy = 0.0f; }
    rec = (face * HW + yi) * HW + xi;
}

__device__ inline void nb_fetch(const float4* __restrict__ nb, int rec,
                                float wx, float wy, float c[3]) {
    H8U qa, qb;
    qa.f4 = nb[(size_t)rec * 2 + 0];
    qb.f4 = nb[(size_t)rec * 2 + 1];
#pragma unroll
    for (int k = 0; k < 3; ++k) {
        float top = __half2float(qa.h[k]) * (1.0f - wx) + __half2float(qa.h[4 + k]) * wx;
        float bot = __half2float(qb.h[k]) * (1.0f - wx) + __half2float(qb.h[4 + k]) * wx;
        c[k] = top * (1.0f - wy) + bot * wy;
    }
}

// ---------------------------------------------------------------------------
// 8B half4 texels, 2-row-paired tiled layout (bg1p fallback):
// float2 element ((face*H/2 + y/2)*W + x)*2 + (y&1)
// ---------------------------------------------------------------------------
struct BLT {
    int i00, i10, i01, i11;
    float wx, wy;
};

__device__ inline BLT bl_tiled(float u, float v, int H, int W, int face) {
    float fx = u * (float)W - 0.5f;
    float fy = v * (float)H - 0.5f;
    float x0 = floorf(fx), y0 = floorf(fy);
    BLT b;
    b.wx = fx - x0;
    b.wy = fy - y0;
    int x0i = min(max((int)x0, 0), W - 1);
    int x1i = min(max((int)x0 + 1, 0), W - 1);
    int y0i = min(max((int)y0, 0), H - 1);
    int y1i = min(max((int)y0 + 1, 0), H - 1);
    int fb = face * (H >> 1);
    int r0 = (fb + (y0i >> 1)) * W;
    int r1 = (fb + (y1i >> 1)) * W;
    b.i00 = (r0 + x0i) * 2 + (y0i & 1);
    b.i10 = (r0 + x1i) * 2 + (y0i & 1);
    b.i01 = (r1 + x0i) * 2 + (y1i & 1);
    b.i11 = (r1 + x1i) * 2 + (y1i & 1);
    return b;
}

__device__ inline void fetch_bl(const float2* __restrict__ tex,
                                const BLT& b, float c[3]) {
    H4U t00, t10, t01, t11;
    t00.f2 = tex[b.i00];
    t10.f2 = tex[b.i10];
    t01.f2 = tex[b.i01];
    t11.f2 = tex[b.i11];
    float wx = b.wx, wy = b.wy;
#pragma unroll
    for (int k = 0; k < 3; ++k) {
        float top = __half2float(t00.h[k]) * (1.0f - wx) + __half2float(t10.h[k]) * wx;
        float bot = __half2float(t01.h[k]) * (1.0f - wx) + __half2float(t11.h[k]) * wx;
        c[k] = top * (1.0f - wy) + bot * wy;
    }
}

// ---------------------------------------------------------------------------
// Interleaved blur records: per 128-map texel, 4 levels x half4 = 32B.
// rec = ((face*64 + y/2)*128 + x)*2 + (y&1)
// ---------------------------------------------------------------------------
struct BLR {
    int r00, r10, r01, r11;
    float wx, wy;
};

__device__ inline BLR bl_rec(float u, float v, int face) {
    float fx = u * 128.0f - 0.5f;
    float fy = v * 128.0f - 0.5f;
    float x0 = floorf(fx), y0 = floorf(fy);
    BLR b;
    b.wx = fx - x0;
    b.wy = fy - y0;
    int x0i = min(max((int)x0, 0), 127);
    int x1i = min(max((int)x0 + 1, 0), 127);
    int y0i = min(max((int)y0, 0), 127);
    int y1i = min(max((int)y0 + 1, 0), 127);
    int fb = face * 64;
    int r0 = (fb + (y0i >> 1)) * 128;
    int r1 = (fb + (y1i >> 1)) * 128;
    b.r00 = (r0 + x0i) * 2 + (y0i & 1);
    b.r10 = (r0 + x1i) * 2 + (y0i & 1);
    b.r01 = (r1 + x0i) * 2 + (y1i & 1);
    b.r11 = (r1 + x1i) * 2 + (y1i & 1);
    return b;
}

__device__ inline void accum_level(const H8U& q00, const H8U& q10,
                                   const H8U& q01, const H8U& q11,
                                   int off, float w, float wx, float wy,
                                   float& b0, float& b1, float& b2) {
    float c[3];
#pragma unroll
    for (int k = 0; k < 3; ++k) {
        float top = __half2float(q00.h[off + k]) * (1.0f - wx) + __half2float(q10.h[off + k]) * wx;
        float bot = __half2float(q01.h[off + k]) * (1.0f - wx) + __half2float(q11.h[off + k]) * wx;
        c[k] = top * (1.0f - wy) + bot * wy;
    }
    b0 += w * c[0];
    b1 += w * c[1];
    b2 += w * c[2];
}

// ---------------------------------------------------------------------------
// Inline f32 Gaussian weights (tid 0..127 -> lvl=tid/32, tap=tid%32)
// ---------------------------------------------------------------------------
__device__ inline void weights_inline(int tid, float wS[4][32]) {
    const float ss[4] = {8.f, 4.f, 2.f, 1.f};
    int lvl = (tid >> 5) & 3;
    int tap = tid & 31;
    float d = (float)tap - 15.0f;
    float q = d / ss[lvl];
    float g = (tap < KSIZE) ? expf(-0.5f * q * q) : 0.0f;
    float s = g;
#pragma unroll
    for (int k = 16; k; k >>= 1) s += __shfl_xor(s, k, 32);
    if (tid < 128) wS[lvl][tap] = g / s;
}

// ---------------------------------------------------------------------------
// FUSED prep kernel #1:
//   blocks [0, 6144)      : pack bg1 (nbhd records if NB1, else tiled half4)
//   blocks [6144, 6528)   : horizontal 4-level blur (2 rows/block) + bg0n emit
// tmpH: per 128-texel 32B = {lvl0 rgb, lvl1 rgb | lvl2 rgb, lvl3 rgb} halves
// ---------------------------------------------------------------------------
template <bool NB1>
__global__ __launch_bounds__(256)
void prep1(const float* __restrict__ bg0, const float* __restrict__ bg1,
           float4* __restrict__ tmpH, float4* __restrict__ bg0n,
           float4* __restrict__ bg1n, float2* __restrict__ bg1p) {
    __shared__ float sm[2 * 2 * 384 + 4 * 32];   // rows + weights (blur branch)
    int b = blockIdx.x;

    if (b < 6144) {
        // ---- bg1 pack branch ----
        if (NB1) {
            __shared__ float t[17][17 * 3];
            int bx = b & 31;
            int by = (b >> 5) & 31;
            int f  = b >> 10;
            for (int i = threadIdx.x; i < 17 * 17; i += 256) {
                int lx = i % 17, ly = i / 17;
                int gx = min(bx * 16 + lx, 511);
                int gy = min(by * 16 + ly, 511);
                const float* p = bg1 + ((size_t)(f * 512 + gy) * 512 + gx) * 3;
                t[ly][lx * 3 + 0] = p[0];
                t[ly][lx * 3 + 1] = p[1];
                t[ly][lx * 3 + 2] = p[2];
            }
            __syncthreads();
            int tx = threadIdx.x & 15, ty = threadIdx.x >> 4;
            H8U qa, qb;
#pragma unroll
            for (int k = 0; k < 3; ++k) {
                qa.h[k]     = __float2half(t[ty][tx * 3 + k]);
                qa.h[4 + k] = __float2half(t[ty][(tx + 1) * 3 + k]);
                qb.h[k]     = __float2half(t[ty + 1][tx * 3 + k]);
                qb.h[4 + k] = __float2half(t[ty + 1][(tx + 1) * 3 + k]);
            }
            qa.h[3] = __float2half(0.0f); qa.h[7] = __float2half(0.0f);
            qb.h[3] = __float2half(0.0f); qb.h[7] = __float2half(0.0f);
            size_t rec = (size_t)(f * 512 + by * 16 + ty) * 512 + bx * 16 + tx;
            bg1n[rec * 2 + 0] = qa.f4;
            bg1n[rec * 2 + 1] = qb.f4;
        } else {
            int i = b * 256 + threadIdx.x;       // texel id, 1572864 total
            int x = i & 511;
            int y = (i >> 9) & 511;
            int f = i >> 18;
            H4U u;
            u.h[0] = __float2half(bg1[(size_t)i * 3 + 0]);
            u.h[1] = __float2half(bg1[(size_t)i * 3 + 1]);
            u.h[2] = __float2half(bg1[(size_t)i * 3 + 2]);
            u.h[3] = __float2half(0.0f);
            int idx = ((f * 256 + (y >> 1)) * 512 + x) * 2 + (y & 1);
            bg1p[idx] = u.f2;
        }
        return;
    }

    // ---- horizontal blur branch: 2 rows per block ----
    float (*rows)[2][384] = (float (*)[2][384])sm;
    float (*wS)[32] = (float (*)[32])(sm + 2 * 2 * 384);

    int bid  = b - 6144;               // 0..383
    int unit = threadIdx.x >> 7;       // 0 or 1
    int lane = threadIdx.x & 127;
    int face = bid / 64;
    int yrow = (bid % 64) * 2 + unit;

    weights_inline(threadIdx.x, wS);

    int ynext = min(yrow + 1, 127);
    const float* srcA = bg0 + (size_t)(face * 128 + yrow) * 384;
    const float* srcB = bg0 + (size_t)(face * 128 + ynext) * 384;
    for (int k = lane; k < 384; k += 128) {
        rows[unit][0][k] = srcA[k];
        rows[unit][1][k] = srcB[k];
    }
    __syncthreads();

    int x = lane;
    float a[4][3] = {};
    for (int t = 0; t < KSIZE; ++t) {
        int xx = x + t - HRAD;
        if (xx >= 0 && xx < 128) {
            float r0 = rows[unit][0][xx * 3 + 0];
            float r1 = rows[unit][0][xx * 3 + 1];
            float r2 = rows[unit][0][xx * 3 + 2];
#pragma unroll
            for (int l = 0; l < 4; ++l) {
                float w = wS[l][t];
                a[l][0] += w * r0; a[l][1] += w * r1; a[l][2] += w * r2;
            }
        }
    }
    size_t idx = (size_t)(face * 128 + yrow) * 128 + x;
    H8U ta, tb;
#pragma unroll
    for (int l = 0; l < 2; ++l) {
        ta.h[l * 4 + 0] = __float2half(a[l][0]);
        ta.h[l * 4 + 1] = __float2half(a[l][1]);
        ta.h[l * 4 + 2] = __float2half(a[l][2]);
        ta.h[l * 4 + 3] = __float2half(0.0f);
        tb.h[l * 4 + 0] = __float2half(a[2 + l][0]);
        tb.h[l * 4 + 1] = __float2half(a[2 + l][1]);
        tb.h[l * 4 + 2] = __float2half(a[2 + l][2]);
        tb.h[l * 4 + 3] = __float2half(0.0f);
    }
    tmpH[idx * 2 + 0] = ta.f4;
    tmpH[idx * 2 + 1] = tb.f4;

    // bg0 neighborhood record for (x, yrow)
    int x1 = min(x + 1, 127);
    H8U qa, qb;
#pragma unroll
    for (int k = 0; k < 3; ++k) {
        qa.h[k]     = __float2half(rows[unit][0][x * 3 + k]);
        qa.h[4 + k] = __float2half(rows[unit][0][x1 * 3 + k]);
        qb.h[k]     = __float2half(rows[unit][1][x * 3 + k]);
        qb.h[4 + k] = __float2half(rows[unit][1][x1 * 3 + k]);
    }
    qa.h[3] = __float2half(0.0f); qa.h[7] = __float2half(0.0f);
    qb.h[3] = __float2half(0.0f); qb.h[7] = __float2half(0.0f);
    bg0n[idx * 2 + 0] = qa.f4;
    bg0n[idx * 2 + 1] = qb.f4;
}

// ---------------------------------------------------------------------------
// Vertical blur: one output row per block; 2 float4 loads per tap row.
// ---------------------------------------------------------------------------
__global__ __launch_bounds__(128)
void blur_v4(const float4* __restrict__ tmpH, float4* __restrict__ blurp) {
    __shared__ float wS[4][32];
    int bid  = blockIdx.x;
    int yrow = bid & 127;
    int face = bid >> 7;
    int tid  = threadIdx.x;

    weights_inline(tid, wS);
    __syncthreads();

    int x = tid;
    float acc[12] = {};
    int ylo = max(yrow - HRAD, 0);
    int yhi = min(yrow + HRAD, 127);
    for (int yy = ylo; yy <= yhi; ++yy) {
        int t = yy - yrow + HRAD;
        size_t idx = (size_t)(face * 128 + yy) * 128 + x;
        H8U qa, qb;
        qa.f4 = tmpH[idx * 2 + 0];
        qb.f4 = tmpH[idx * 2 + 1];
        float w0 = wS[0][t], w1 = wS[1][t], w2 = wS[2][t], w3 = wS[3][t];
        acc[0]  += w0 * __half2float(qa.h[0]);
        acc[1]  += w0 * __half2float(qa.h[1]);
        acc[2]  += w0 * __half2float(qa.h[2]);
        acc[3]  += w1 * __half2float(qa.h[4]);
        acc[4]  += w1 * __half2float(qa.h[5]);
        acc[5]  += w1 * __half2float(qa.h[6]);
        acc[6]  += w2 * __half2float(qb.h[0]);
        acc[7]  += w2 * __half2float(qb.h[1]);
        acc[8]  += w2 * __half2float(qb.h[2]);
        acc[9]  += w3 * __half2float(qb.h[4]);
        acc[10] += w3 * __half2float(qb.h[5]);
        acc[11] += w3 * __half2float(qb.h[6]);
    }

    H8U ra, rb;
#pragma unroll
    for (int l = 0; l < 2; ++l) {
        ra.h[l * 4 + 0] = __float2half(acc[l * 3 + 0]);
        ra.h[l * 4 + 1] = __float2half(acc[l * 3 + 1]);
        ra.h[l * 4 + 2] = __float2half(acc[l * 3 + 2]);
        ra.h[l * 4 + 3] = __float2half(0.0f);
        rb.h[l * 4 + 0] = __float2half(acc[6 + l * 3 + 0]);
        rb.h[l * 4 + 1] = __float2half(acc[6 + l * 3 + 1]);
        rb.h[l * 4 + 2] = __float2half(acc[6 + l * 3 + 2]);
        rb.h[l * 4 + 3] = __float2half(0.0f);
    }
    int rec = ((face * 64 + (yrow >> 1)) * 128 + x) * 2 + (yrow & 1);
    blurp[(size_t)rec * 2 + 0] = ra.f4;
    blurp[(size_t)rec * 2 + 1] = rb.f4;
}

// ---------------------------------------------------------------------------
// Per-ray shading body (r6-proven)
// ---------------------------------------------------------------------------
template <bool NB1>
__device__ inline void shade_one(float x, float y, float z, float sa,
                                 const float4* __restrict__ bg0n,
                                 const float4* __restrict__ bg1n,
                                 const float2* __restrict__ bg1p,
                                 const float4* __restrict__ blurp,
                                 float* __restrict__ R) {
    int face; float u, v;
    cube_coords(x, y, z, face, u, v);

    const float saTexel = (float)(4.0 * M_PI / (6.0 * 512.0 * 512.0));
    float m = logf(sa / saTexel);
    m = m / 1.3862943611198906f;   // f32(log(4))
    m = m * 0.5f;
    m = fminf(fmaxf(m, 0.0f), 3.0f);

    if (m >= 2.0f) {
        BLR b = bl_rec(u, v, face);
        H8U q00a, q00b, q10a, q10b, q01a, q01b, q11a, q11b;
        q00a.f4 = blurp[b.r00 * 2 + 0]; q00b.f4 = blurp[b.r00 * 2 + 1];
        q10a.f4 = blurp[b.r10 * 2 + 0]; q10b.f4 = blurp[b.r10 * 2 + 1];
        q01a.f4 = blurp[b.r01 * 2 + 0]; q01b.f4 = blurp[b.r01 * 2 + 1];
        q11a.f4 = blurp[b.r11 * 2 + 0]; q11b.f4 = blurp[b.r11 * 2 + 1];

        float w0 = 1.0f - fminf(fabsf(3.0f - m), 1.0f);
        float w1 = 1.0f - fminf(fabsf(2.5f - m), 1.0f);
        float w2 = 1.0f - fminf(fabsf(2.0f - m), 1.0f);
        float w3 = 1.0f - fminf(fabsf(1.5f - m), 1.0f);

        float b0 = 0.f, b1 = 0.f, b2 = 0.f;
        accum_level(q00a, q10a, q01a, q11a, 0, w0, b.wx, b.wy, b0, b1, b2);
        accum_level(q00a, q10a, q01a, q11a, 4, w1, b.wx, b.wy, b0, b1, b2);
        accum_level(q00b, q10b, q01b, q11b, 0, w2, b.wx, b.wy, b0, b1, b2);
        accum_level(q00b, q10b, q01b, q11b, 4, w3, b.wx, b.wy, b0, b1, b2);

        float denom = fmaxf(w0 + w1 + w2 + w3, 1e-8f);
        R[0] = b0 / denom; R[1] = b1 / denom; R[2] = b2 / denom;
    } else {
        int r0i; float wx0, wy0;
        nb_setup(u, v, 128, face, r0i, wx0, wy0);
        float c0[3], c1[3];
        nb_fetch(bg0n, r0i, wx0, wy0, c0);
        if (NB1) {
            int r1i; float wx1, wy1;
            nb_setup(u, v, 512, face, r1i, wx1, wy1);
            nb_fetch(bg1n, r1i, wx1, wy1, c1);
        } else {
            BLT b512 = bl_tiled(u, v, 512, 512, face);
            fetch_bl(bg1p, b512, c1);
        }
        R[0] = c0[0] + 0.5f * c1[0];
        R[1] = c0[1] + 0.5f * c1[1];
        R[2] = c0[2] + 0.5f * c1[2];
    }
}

// ---------------------------------------------------------------------------
// Shade: 4 rays per thread, vectorized stream I/O (r6-proven structure).
// ---------------------------------------------------------------------------
template <bool NB1>
__global__ __launch_bounds__(256)
void shade4(const float4* __restrict__ vd4, const float4* __restrict__ sa4,
            const float4* __restrict__ bg0n, const float4* __restrict__ bg1n,
            const float2* __restrict__ bg1p, const float4* __restrict__ blurp,
            float4* __restrict__ out4, int nquads) {
    int q = blockIdx.x * blockDim.x + threadIdx.x;
    if (q >= nquads) return;

    float4 a = vd4[3 * q + 0];
    float4 b = vd4[3 * q + 1];
    float4 c = vd4[3 * q + 2];
    float4 s = sa4[q];

    float X[4] = {a.x, a.w, b.z, c.y};
    float Y[4] = {a.y, b.x, b.w, c.z};
    float Z[4] = {a.z, b.y, c.x, c.w};
    float S[4] = {s.x, s.y, s.z, s.w};

    float R[12];
#pragma unroll
    for (int r = 0; r < 4; ++r) {
        shade_one<NB1>(X[r], Y[r], Z[r], S[r], bg0n, bg1n, bg1p, blurp, &R[3 * r]);
    }

    out4[3 * q + 0] = make_float4(R[0], R[1], R[2],  R[3]);
    out4[3 * q + 1] = make_float4(R[4], R[5], R[6],  R[7]);
    out4[3 * q + 2] = make_float4(R[8], R[9], R[10], R[11]);
}

// ---------------------------------------------------------------------------
extern "C" void kernel_launch(void* const* d_in, const int* in_sizes, int n_in,
                              void* d_out, int out_size, void* d_ws, size_t ws_size,
                              hipStream_t stream) {
    const float* viewdirs = (const float*)d_in[0];   // (B,3)
    const float* saSample = (const float*)d_in[1];   // (B,1)
    const float* bg0      = (const float*)d_in[2];   // (6,128,128,3)
    const float* bg1      = (const float*)d_in[3];   // (6,512,512,3)
    float* out = (float*)d_out;

    int B = in_sizes[0] / 3;          // 2097152
    int nquads = B / 4;

    // Tier A (59.77 MB): blurp 196608 f4 | bg0n 196608 f4 | bg1n 3145728 f4
    //                    | tmpH 196608 f4
    // Tier B (22.0 MB):  blurp | bg0n | bg1p 1572864 f2 | tmpH 196608 f4
    float4* blurp = (float4*)d_ws;
    float4* bg0n  = blurp + 196608;
    const size_t NEED_A = (size_t)(196608 * 3 + 3145728) * 16;
    bool nb1 = ws_size >= NEED_A;

    float4* bg1n = bg0n + 196608;
    float2* bg1p = (float2*)(bg0n + 196608);
    float4* tmpH = nb1 ? (bg1n + 3145728) : (float4*)(bg1p + 1572864);

    if (nb1) {
        prep1<true><<<6528, 256, 0, stream>>>(bg0, bg1, tmpH, bg0n, bg1n, bg1p);
    } else {
        prep1<false><<<6528, 256, 0, stream>>>(bg0, bg1, tmpH, bg0n, bg1n, bg1p);
    }
    blur_v4<<<6 * 128, 128, 0, stream>>>(tmpH, blurp);

    int blocks = (nquads + 255) / 256;
    if (nb1) {
        shade4<true><<<blocks, 256, 0, stream>>>((const float4*)viewdirs,
                                                 (const float4*)saSample,
                                                 bg0n, bg1n, bg1p, blurp,
                                                 (float4*)out, nquads);
    } else {
        shade4<false><<<blocks, 256, 0, stream>>>((const float4*)viewdirs,
                                                  (const float4*)saSample,
                                                  bg0n, bg1n, bg1p, blurp,
                                                  (float4*)out, nquads);
    }
}